// Round 1
// baseline (113.586 us; speedup 1.0000x reference)
//
#include <hip/hip_runtime.h>

#define NMS_NUM_CLASSES 16
#define NMS_N 2048
#define NMS_IOU_TH 0.5f
#define NMS_SCORE_TH 0.05f
#define NMS_MAX_DET 100
#define NMS_MAX_PER_CLASS 100
#define NMS_NS (NMS_NUM_CLASSES * NMS_MAX_PER_CLASS)   // 1600
#define NMS_TILE 128
#define NMS_TW 4                     // u32 words per column mask (128 bits)

// SESSION PITFALLS (r1-r20):
//  * float4 casts on __shared__ float -> ds_read_b128 misalignment fault.
//  * u64 LDS arrays / LDS pointer casts correlated with container deaths.
//    ONLY declared __shared__ float/uint/uchar arrays, scalar access.
//  * Serial NMS chains cost 45-65 us at M~122 -> Jacobi fixpoint (r15).
//  * Fusion via grid.sync REGRESSED (+5us): launch gaps ~1.4us in graphs.
//  * r19 amplification: k1 = F + W with F~2us, W~37us -> latency-bound on
//    ~15 barrier phases, not dispatch overhead and not HBM.
//  * r20 (this round): phase-count cut 14 -> ~8.
//      - Jacobi 1 barrier/round: double-buffered s_kwds[2][] + s_wchg[2][]
//        (round r reads buf r&1, publishes r&1^1; uniform break via freshly
//        published change flags -> no divergent-barrier hazard).
//      - init keep-ballot publish fused into the supc barrier (it only
//        depends on s_keep, which is final since the scatter/A0 barrier).
//      - emit: wave-0-only count + shfl-scan + write + pad, 0 extra barriers
//        (replaces 256-thread count/scan phases; s_part/s_total deleted).

// ---------------------------------------------------------------------------
// Kernel 1: one block per (image, class), 1024 threads.
// Wave-aggregated compact (+ fused s_rk zeroing) -> task-parallel rank sort
// -> column-mask + 1-barrier Jacobi NMS -> wave-0 scan emit.
// ---------------------------------------------------------------------------
__global__ __launch_bounds__(1024) void nms_per_class_kernel(
    const float* __restrict__ pred,   // [B, N, 6] x1,y1,x2,y2,cls,score
    float* __restrict__ ws_scores,    // [B, 1600]
    float* __restrict__ ws_boxes,     // [B, 1600, 4]
    float* __restrict__ out,          // [B*600] rows + [B] nvalid
    int B)
{
    const int b = blockIdx.x / NMS_NUM_CLASSES;
    const int c = blockIdx.x % NMS_NUM_CLASSES;
    const float* p = pred + (size_t)b * NMS_N * 6;

    // zero-init output for this image (k2 is a later dispatch on the stream)
    if (c == 0) {
        float* ob = out + (size_t)b * NMS_MAX_DET * 6;
        for (int t = threadIdx.x; t < NMS_MAX_DET * 6; t += blockDim.x) ob[t] = 0.0f;
        if (threadIdx.x == 0) out[(size_t)B * NMS_MAX_DET * 6 + b] = 0.0f;
    }

    // unsorted candidate arrays
    __shared__ float s_scu[NMS_N];
    __shared__ int   s_ixu[NMS_N];
    __shared__ float s_bxu[NMS_N * 4];
    __shared__ int   s_rk[NMS_N];
    // sorted candidate arrays
    __shared__ float s_sc[NMS_N];
    __shared__ float s_bx[NMS_N * 4];
    __shared__ unsigned char s_keep[NMS_N];
    __shared__ unsigned int s_supc[NMS_TILE * NMS_TW];  // column masks, 2 KB
    __shared__ unsigned int s_kwds[2][NMS_TW];          // double-buffered keep bits
    __shared__ unsigned int s_wchg[2][2];               // double-buffered change flags
    __shared__ int s_m;

    if (threadIdx.x == 0) s_m = 0;
    __syncthreads();

    // --- wave-aggregated compact of class-c candidates (score > TH);
    //     s_rk zeroing fused into the same phase (covered by one barrier) ---
    const float2* p2 = (const float2*)p;   // row i = p2[3i], p2[3i+1], p2[3i+2]
    for (int i = threadIdx.x; i < NMS_N; i += blockDim.x) {   // uniform trips
        s_rk[i] = 0;                 // fused zero-init (rank phase reads after barrier)
        float2 v0 = p2[i * 3 + 0];   // x1, y1
        float2 v1 = p2[i * 3 + 1];   // x2, y2
        float2 v2 = p2[i * 3 + 2];   // cls, score
        const bool ok = ((int)v2.x == c) && (v2.y > NMS_SCORE_TH);
        unsigned long long mask = __ballot(ok);
        const int lane = threadIdx.x & 63;
        int base = 0;
        if (lane == 0) {
            int cnt = __popcll(mask);
            if (cnt) base = atomicAdd(&s_m, cnt);
        }
        base = __shfl(base, 0, 64);
        if (ok) {
            int pos = base + __popcll(mask & ((1ull << lane) - 1ull));
            s_scu[pos] = v2.y;
            s_ixu[pos] = i;
            s_bxu[pos * 4 + 0] = v0.x;
            s_bxu[pos * 4 + 1] = v0.y;
            s_bxu[pos * 4 + 2] = v1.x;
            s_bxu[pos * 4 + 3] = v1.y;
        }
    }
    __syncthreads();
    const int M = s_m;

    // --- task-parallel rank sort (r16-proven; s_rk pre-zeroed above) ---
    {
        const int nch = (M + 31) >> 5;
        const int ntask = M * nch;
        for (int task = threadIdx.x; task < ntask; task += blockDim.x) {
            const int q = task % M;          // consecutive tids -> distinct q
            const int ch = task / M;
            const float sq = s_scu[q];
            const int   iq = s_ixu[q];
            const int j0 = ch << 5;
            int jend = j0 + 32; if (jend > M) jend = M;
            int rk = 0;
            for (int j = j0; j < jend; ++j) {
                float sj = s_scu[j];
                rk += (sj > sq) || (sj == sq && s_ixu[j] < iq);
            }
            if (rk) atomicAdd(&s_rk[q], rk);
        }
    }
    __syncthreads();
    for (int q = threadIdx.x; q < M; q += blockDim.x) {
        int rk = s_rk[q];
        s_sc[rk] = s_scu[q];
        s_bx[rk * 4 + 0] = s_bxu[q * 4 + 0];
        s_bx[rk * 4 + 1] = s_bxu[q * 4 + 1];
        s_bx[rk * 4 + 2] = s_bxu[q * 4 + 2];
        s_bx[rk * 4 + 3] = s_bxu[q * 4 + 3];
        s_keep[rk] = 1;
    }
    __syncthreads();

    // --- tiled NMS: column masks + 1-barrier Jacobi fixpoint per tile ---
    for (int t0 = 0; t0 < M; t0 += NMS_TILE) {
        const int tm = (M - t0 < NMS_TILE) ? (M - t0) : NMS_TILE;

        // A0: suppression by kept candidates of earlier tiles (final state)
        if (t0 > 0) {
            for (int jj = threadIdx.x; jj < tm; jj += blockDim.x) {
                const int gj = t0 + jj;
                float jx1 = s_bx[gj * 4 + 0], jy1 = s_bx[gj * 4 + 1];
                float jx2 = s_bx[gj * 4 + 2], jy2 = s_bx[gj * 4 + 3];
                float aj = (jy2 - jy1) * (jx2 - jx1);
                int dead = 0;
                for (int i = 0; i < t0 && !dead; ++i) {
                    if (!s_keep[i]) continue;
                    float ix1 = s_bx[i * 4 + 0], iy1 = s_bx[i * 4 + 1];
                    float ix2 = s_bx[i * 4 + 2], iy2 = s_bx[i * 4 + 3];
                    float ai = (iy2 - iy1) * (ix2 - ix1);
                    float ih = fminf(iy2, jy2) - fmaxf(iy1, jy1);
                    ih = fmaxf(ih, 0.0f);
                    float iw = fminf(ix2, jx2) - fmaxf(ix1, jx1);
                    iw = fmaxf(iw, 0.0f);
                    float inter = ih * iw;
                    float uni = ai + aj - inter;
                    float iou = (inter > 0.0f) ? inter / fmaxf(uni, 1e-08f) : 0.0f;
                    dead = iou > NMS_IOU_TH;
                }
                if (dead) s_keep[gj] = 0;
            }
            __syncthreads();
        }

        // A: column suppressor masks — (wi, j) task space in one sweep
        for (int idx = threadIdx.x; idx < NMS_TW * tm; idx += blockDim.x) {
            const int wi = idx / tm;
            const int jj = idx % tm;
            const int ibase = wi << 5;
            unsigned int msk = 0;
            int iend = jj - ibase;           // only i < j
            if (iend > 32) iend = 32;
            if (iend > 0) {
                const int gj = t0 + jj;
                float jx1 = s_bx[gj * 4 + 0], jy1 = s_bx[gj * 4 + 1];
                float jx2 = s_bx[gj * 4 + 2], jy2 = s_bx[gj * 4 + 3];
                float aj = (jy2 - jy1) * (jx2 - jx1);
                for (int bb = 0; bb < iend; ++bb) {
                    const int gi = t0 + ibase + bb;
                    float ix1 = s_bx[gi * 4 + 0], iy1 = s_bx[gi * 4 + 1];
                    float ix2 = s_bx[gi * 4 + 2], iy2 = s_bx[gi * 4 + 3];
                    float ai = (iy2 - iy1) * (ix2 - ix1);
                    float ih = fminf(iy2, jy2) - fmaxf(iy1, jy1);
                    ih = fmaxf(ih, 0.0f);
                    float iw = fminf(ix2, jx2) - fmaxf(ix1, jx1);
                    iw = fmaxf(iw, 0.0f);
                    float inter = ih * iw;
                    float uni = ai + aj - inter;
                    float iou = (inter > 0.0f) ? inter / fmaxf(uni, 1e-08f) : 0.0f;
                    if (iou > NMS_IOU_TH) msk |= (1u << bb);
                }
            }
            s_supc[jj * NMS_TW + wi] = msk;
        }

        // Jacobi init: thread j owns tile candidate j. The initial keep
        // ballot depends only on s_keep (final since scatter/A0 barrier),
        // so its publish shares the supc barrier below.
        const int j = threadIdx.x;
        int ext = 0;                 // pre-suppression state (A0 deaths final)
        if (j < tm) ext = s_keep[t0 + j];
        int alive = ext;
        {
            unsigned long long bal = __ballot(alive != 0);
            if ((threadIdx.x & 63) == 0 && threadIdx.x < NMS_TILE) {
                s_kwds[0][(threadIdx.x >> 6) * 2 + 0] = (unsigned int)(bal & 0xffffffffu);
                s_kwds[0][(threadIdx.x >> 6) * 2 + 1] = (unsigned int)(bal >> 32);
            }
        }
        __syncthreads();             // supc + kwds[0] complete

        // 1 barrier per round: round r reads s_kwds[r&1], publishes r&1^1.
        // Break decision reads only freshly-published flags -> uniform.
        for (int round = 0; ; ++round) {
            const int rb = round & 1;
            int newalive = 0;
            if (j < tm && ext) {
                unsigned int any = (s_supc[j * NMS_TW + 0] & s_kwds[rb][0])
                                 | (s_supc[j * NMS_TW + 1] & s_kwds[rb][1])
                                 | (s_supc[j * NMS_TW + 2] & s_kwds[rb][2])
                                 | (s_supc[j * NMS_TW + 3] & s_kwds[rb][3]);
                newalive = (any == 0);
            }
            const int ch = (newalive != alive);
            alive = newalive;
            unsigned long long bal = __ballot(alive != 0);
            unsigned long long chb = __ballot(ch != 0);
            if ((threadIdx.x & 63) == 0 && threadIdx.x < NMS_TILE) {
                s_kwds[rb ^ 1][(threadIdx.x >> 6) * 2 + 0] = (unsigned int)(bal & 0xffffffffu);
                s_kwds[rb ^ 1][(threadIdx.x >> 6) * 2 + 1] = (unsigned int)(bal >> 32);
                s_wchg[rb ^ 1][threadIdx.x >> 6] = (chb != 0ull) ? 1u : 0u;
            }
            __syncthreads();         // publish visible; prior-buffer reads done
            if ((s_wchg[rb ^ 1][0] | s_wchg[rb ^ 1][1]) == 0u) break;  // uniform
            if (round >= tm) break;  // safety bound (uniform)
        }

        if (j < tm) s_keep[t0 + j] = (unsigned char)alive;
        __syncthreads();
    }

    // --- emit top-100 kept in sorted order: wave 0 only, zero extra barriers
    //     (count + shfl-scan + write + pad all within one wave) ---
    if (threadIdx.x < 64) {
        const int lane = threadIdx.x;
        const int chunk = (M + 63) >> 6;         // contiguous slots per lane
        int lo = lane * chunk;
        int hi = lo + chunk; if (hi > M) hi = M;
        int cnt = 0;
        for (int jj = lo; jj < hi; ++jj) cnt += s_keep[jj];
        int inc = cnt;
        for (int off = 1; off < 64; off <<= 1) {
            int n = __shfl_up(inc, off, 64);
            if (lane >= off) inc += n;
        }
        int pos = inc - cnt;                     // exclusive prefix
        const int total = __shfl(inc, 63, 64);

        float* osc = ws_scores + ((size_t)b * NMS_NUM_CLASSES + c) * NMS_MAX_PER_CLASS;
        float* obx = ws_boxes + (((size_t)b * NMS_NUM_CLASSES + c) * NMS_MAX_PER_CLASS) * 4;
        for (int jj = lo; jj < hi; ++jj) {
            if (s_keep[jj]) {
                if (pos < NMS_MAX_PER_CLASS) {
                    osc[pos] = s_sc[jj];
                    obx[pos * 4 + 0] = s_bx[jj * 4 + 0];
                    obx[pos * 4 + 1] = s_bx[jj * 4 + 1];
                    obx[pos * 4 + 2] = s_bx[jj * 4 + 2];
                    obx[pos * 4 + 3] = s_bx[jj * 4 + 3];
                }
                pos++;
            }
        }
        // pad positions [total, 100) with -1 (lane covers lane and lane+64)
        for (int pp = lane; pp < NMS_MAX_PER_CLASS; pp += 64) {
            if (pp >= total) osc[pp] = -1.0f;
        }
    }
}

// ---------------------------------------------------------------------------
// Kernel 2: one block per (image, class), 256 threads. Task-parallel partial
// ranks. BYTE-IDENTICAL to round-12 (passed, absmax 0).
// ---------------------------------------------------------------------------
__global__ __launch_bounds__(256) void nms_topk_kernel(
    const float* __restrict__ ws_scores,   // [B, 1600]
    const float* __restrict__ ws_boxes,    // [B, 1600, 4]
    float* __restrict__ out,               // [B*600] rows + [B] nvalid
    int B)
{
    const int b = blockIdx.x / NMS_NUM_CLASSES;
    const int c = blockIdx.x % NMS_NUM_CLASSES;
    const int cbase = c * NMS_MAX_PER_CLASS;
    __shared__ float s_sc[NMS_NS];
    __shared__ int s_rank[NMS_MAX_PER_CLASS];

    const float* isc = ws_scores + (size_t)b * NMS_NS;
    for (int t = threadIdx.x; t < NMS_NS; t += blockDim.x) s_sc[t] = isc[t];
    if (threadIdx.x < NMS_MAX_PER_CLASS) s_rank[threadIdx.x] = 0;
    __syncthreads();

    for (int task = threadIdx.x; task < NMS_MAX_PER_CLASS * 16; task += blockDim.x) {
        const int slot = task % NMS_MAX_PER_CLASS;
        const int chunk = task / NMS_MAX_PER_CLASS;
        const int flat = cbase + slot;
        const float s = s_sc[flat];
        const int j0 = chunk * 100;
        int rk = 0;
        for (int j = j0; j < j0 + 100; ++j) {
            float sj = s_sc[j];
            rk += (sj > s) || (sj == s && j < flat);
        }
        if (rk) atomicAdd(&s_rank[slot], rk);
    }
    __syncthreads();

    int is_top = 0;
    const int t = threadIdx.x;
    if (t < NMS_MAX_PER_CLASS) {
        const int slot = cbase + t;
        float s = s_sc[slot];
        if (s > NMS_SCORE_TH) {
            int rk = s_rank[t];
            if (rk < NMS_MAX_DET) {
                const float* bx = ws_boxes + ((size_t)b * NMS_NS + slot) * 4;
                float* row = out + (size_t)b * NMS_MAX_DET * 6 + rk * 6;
                row[0] = bx[0];
                row[1] = bx[1];
                row[2] = bx[2];
                row[3] = bx[3];
                row[4] = (float)c;
                row[5] = s;
                is_top = 1;
            }
        }
    }
    unsigned long long m = __ballot(is_top);
    if ((threadIdx.x & 63) == 0) {
        float cnt = (float)__popcll(m);
        if (cnt > 0.0f)
            atomicAdd(&out[(size_t)B * NMS_MAX_DET * 6 + b], cnt);
    }
}

extern "C" void kernel_launch(void* const* d_in, const int* in_sizes, int n_in,
                              void* d_out, int out_size, void* d_ws, size_t ws_size,
                              hipStream_t stream) {
    const float* pred = (const float*)d_in[0];
    const int B = in_sizes[0] / (NMS_N * 6);
    if (B <= 0) return;
    float* out = (float*)d_out;

    float* ws_scores = (float*)d_ws;
    float* ws_boxes = ws_scores + (size_t)B * NMS_NS;

    nms_per_class_kernel<<<dim3(B * NMS_NUM_CLASSES), dim3(1024), 0, stream>>>(
        pred, ws_scores, ws_boxes, out, B);
    nms_topk_kernel<<<dim3(B * NMS_NUM_CLASSES), dim3(256), 0, stream>>>(
        ws_scores, ws_boxes, out, B);
}